// Round 6
// baseline (392.906 us; speedup 1.0000x reference)
//
#include <hip/hip_runtime.h>

typedef unsigned short u16;
typedef __attribute__((ext_vector_type(4))) float floatx4;
typedef __attribute__((ext_vector_type(8))) short shortx8;

#define B_ 4
#define S_ 2048
#define D_ 1024
#define H_ 16
#define HD_ 64

__device__ __forceinline__ float b2f(u16 u) {
    return __uint_as_float(((unsigned int)u) << 16);
}
__device__ __forceinline__ u16 f2b(float f) {
    unsigned int u = __float_as_uint(f);
    u += 0x7fffu + ((u >> 16) & 1u);
    return (u16)(u >> 16);
}
__device__ __forceinline__ unsigned long long pack4(float a, float b, float c, float d) {
    return (unsigned long long)f2b(a) | ((unsigned long long)f2b(b) << 16) |
           ((unsigned long long)f2b(c) << 32) | ((unsigned long long)f2b(d) << 48);
}
// async global->LDS, 16B per lane; LDS dest = wave-uniform base + lane*16
__device__ __forceinline__ void glds16(const u16* g, u16* l) {
    __builtin_amdgcn_global_load_lds(
        (const __attribute__((address_space(1))) unsigned int*)g,
        (__attribute__((address_space(3))) unsigned int*)l, 16, 0, 0);
}

// ---------------------------------------------------------------------------
// Dtype detector: bf16 -> flag=1, fp32 -> flag=0.
// ---------------------------------------------------------------------------
__global__ void detect_dtype(const unsigned int* __restrict__ x, int* __restrict__ flag) {
    const int l = threadIdx.x;  // 64 threads
    int cnt = 0;
    for (int i = l; i < 4096; i += 64) {
        const unsigned int e = (x[i] >> 7) & 0xffu;
        cnt += (e >= 110u && e <= 134u) ? 1 : 0;
    }
#pragma unroll
    for (int d = 1; d < 64; d <<= 1) cnt += __shfl_xor(cnt, d);
    if (l == 0) *flag = (cnt > 2048) ? 1 : 0;
}

__global__ __launch_bounds__(256) void convert_x(const void* __restrict__ xin,
                                                 u16* __restrict__ xb,
                                                 const int* __restrict__ flag) {
    const int isbf = *flag;
    const size_t i = ((size_t)blockIdx.x * 256 + threadIdx.x) * 8;
    if (isbf) {
        *(uint4*)(xb + i) = *(const uint4*)((const u16*)xin + i);
    } else {
        const float* xf = (const float*)xin;
        float4 a = *(const float4*)(xf + i);
        float4 b = *(const float4*)(xf + i + 4);
        u16 o[8] = {f2b(a.x), f2b(a.y), f2b(a.z), f2b(a.w),
                    f2b(b.x), f2b(b.y), f2b(b.z), f2b(b.w)};
        *(uint4*)(xb + i) = *(uint4*)o;
    }
}

__global__ void convert_bias(const void* __restrict__ bA, const void* __restrict__ bP,
                             u16* __restrict__ bAb, u16* __restrict__ bPb,
                             const int* __restrict__ flag) {
    const int isbf = *flag;
    for (int i = threadIdx.x; i < 3072; i += 256)
        bAb[i] = isbf ? ((const u16*)bA)[i] : f2b(((const float*)bA)[i]);
    for (int i = threadIdx.x; i < 1024; i += 256)
        bPb[i] = isbf ? ((const u16*)bP)[i] : f2b(((const float*)bP)[i]);
}

// ---------------------------------------------------------------------------
// Transpose (+ dtype normalize): in[K][N] (bf16 or fp32) -> out[N][K] bf16.
// ---------------------------------------------------------------------------
__global__ __launch_bounds__(256) void transpose_any(const void* __restrict__ in,
                                                     u16* __restrict__ out,
                                                     int K, int N,
                                                     const int* __restrict__ flag) {
    const int isbf = *flag;
    __shared__ u16 tile[32][33];
    const int tx = threadIdx.x & 31;
    const int ty = threadIdx.x >> 5;
    const int bx = blockIdx.x * 32;  // N index
    const int by = blockIdx.y * 32;  // K index
    if (isbf) {
#pragma unroll
        for (int i = 0; i < 32; i += 8)
            tile[ty + i][tx] = ((const u16*)in)[(size_t)(by + ty + i) * N + bx + tx];
    } else {
#pragma unroll
        for (int i = 0; i < 32; i += 8)
            tile[ty + i][tx] = f2b(((const float*)in)[(size_t)(by + ty + i) * N + bx + tx]);
    }
    __syncthreads();
#pragma unroll
    for (int i = 0; i < 32; i += 8)
        out[(size_t)(bx + ty + i) * K + by + tx] = tile[tx][ty + i];
}

// ---------------------------------------------------------------------------
// C[M x N] = A[M x K] * BT[N x K]^T + bias.  bf16 in, fp32 accum.
// m97-style: global_load_lds width-16 staging, pitch-32 LDS with XOR chunk
// swizzle (slot = chunk ^ ((row>>1)&3)).
// MODE 0: store to out (bf16 or fp32 per flag).
// MODE 1: QKV scatter into q/k/v ws [b][h][s][64]; Q pre-scaled 0.125*log2e.
// ---------------------------------------------------------------------------
template <int MODE>
__global__ __launch_bounds__(256) void gemm_bt(const u16* __restrict__ A,
                                               const u16* __restrict__ BT,
                                               const u16* __restrict__ bias,
                                               void* __restrict__ outv,
                                               int M, int N, int K,
                                               u16* __restrict__ qws,
                                               u16* __restrict__ kws,
                                               u16* __restrict__ vws,
                                               const int* __restrict__ flag) {
    __shared__ __align__(16) u16 As[128 * 32];
    __shared__ __align__(16) u16 Bs[128 * 32];

    const int isbf = (MODE == 0) ? *flag : 1;
    const int tid = threadIdx.x;
    const int w = tid >> 6, l = tid & 63;
    const int lane_m = l & 15, quad = l >> 4;
    const int bm = blockIdx.x * 128, bn = blockIdx.y * 128;
    const int wm = (w >> 1) * 64, wn = (w & 1) * 64;

    floatx4 acc[4][4];
#pragma unroll
    for (int i = 0; i < 4; i++)
#pragma unroll
        for (int j = 0; j < 4; j++) acc[i][j] = (floatx4){0.f, 0.f, 0.f, 0.f};

    // staging geometry: wave covers 16-row groups rb0, rb1; lane -> (row, slot)
    const int lr = l >> 2, sl = l & 3;
    const int cA = sl ^ ((lr >> 1) & 3);  // logical chunk that lands in slot sl
    const int rb0 = w * 16, rb1 = 64 + w * 16;
    const u16* Arow0 = A + (size_t)(bm + rb0 + lr) * K + cA * 8;
    const u16* Arow1 = A + (size_t)(bm + rb1 + lr) * K + cA * 8;
    const u16* Brow0 = BT + (size_t)(bn + rb0 + lr) * K + cA * 8;
    const u16* Brow1 = BT + (size_t)(bn + rb1 + lr) * K + cA * 8;

    for (int k0 = 0; k0 < K; k0 += 32) {
        __syncthreads();  // prior iteration's frag reads complete
        glds16(Arow0 + k0, As + rb0 * 32);
        glds16(Arow1 + k0, As + rb1 * 32);
        glds16(Brow0 + k0, Bs + rb0 * 32);
        glds16(Brow1 + k0, Bs + rb1 * 32);
        __syncthreads();  // vmcnt(0) drain: tiles resident

        shortx8 af[4], bf[4];
#pragma unroll
        for (int mb = 0; mb < 4; mb++) {
            const int r = wm + mb * 16 + lane_m;
            af[mb] = *(const shortx8*)(As + r * 32 + (quad ^ ((r >> 1) & 3)) * 8);
        }
#pragma unroll
        for (int nb = 0; nb < 4; nb++) {
            const int r = wn + nb * 16 + lane_m;
            bf[nb] = *(const shortx8*)(Bs + r * 32 + (quad ^ ((r >> 1) & 3)) * 8);
        }
#pragma unroll
        for (int mb = 0; mb < 4; mb++)
#pragma unroll
            for (int nb = 0; nb < 4; nb++)
                acc[mb][nb] = __builtin_amdgcn_mfma_f32_16x16x32_bf16(
                    af[mb], bf[nb], acc[mb][nb], 0, 0, 0);
    }

    const float SCALE_Q = 0.18033688011112042f;  // 0.125 * log2(e)
#pragma unroll
    for (int nb = 0; nb < 4; nb++) {
        const int col = bn + wn + nb * 16 + lane_m;
        const float bv = b2f(bias[col]);
#pragma unroll
        for (int mb = 0; mb < 4; mb++) {
            const int rowb = bm + wm + mb * 16 + quad * 4;
#pragma unroll
            for (int r = 0; r < 4; r++) {
                float v = acc[mb][nb][r] + bv;
                const int rr = rowb + r;
                if (MODE == 0) {
                    if (isbf) ((u16*)outv)[(size_t)rr * N + col] = f2b(v);
                    else ((float*)outv)[(size_t)rr * N + col] = v;
                } else {
                    const int which = col >> 10;  // uniform per block
                    if (which == 0) v *= SCALE_Q;
                    const int h = (col >> 6) & 15;
                    const int hd = col & 63;
                    const int b = rr >> 11, s = rr & 2047;
                    u16* dst = which == 0 ? qws : (which == 1 ? kws : vws);
                    dst[((size_t)(b * 16 + h) * 2048 + s) * 64 + hd] = f2b(v);
                }
            }
        }
    }
}

// ---------------------------------------------------------------------------
// Flash attention, causal, transposed-score scheme.
// S^T = K*Q^T (col=q,row=kv) -> in-register softmax; O^T = V^T*P^T.
// K tile staged via global_load_lds (pitch 64, slot = chunk ^ (row&7)).
// Ps pitch 72 (kv-width 64 + pad). Packing via SOFTWARE f2b (round-3 proven;
// round-4/5 hand-asm v_cvt_pk_bf16_f32 produced garbage bits -> 2e30 absmax).
// Block = 256 threads (4 waves); BQ=128 (32 q/wave); BKV=64.
// ---------------------------------------------------------------------------
__global__ __launch_bounds__(256) void attn_kernel(const u16* __restrict__ Qg,
                                                   const u16* __restrict__ Kg,
                                                   const u16* __restrict__ Vg,
                                                   u16* __restrict__ Og) {
    __shared__ __align__(16) u16 Ks[64 * 64];     // K tile [kv][d], chunk-swizzled
    __shared__ __align__(16) u16 Vt[64 * 72];     // V^T tile [d][kv]
    __shared__ __align__(16) u16 Ps[4][32 * 72];  // per-wave P^T as [q][kv]

    const int tid = threadIdx.x, w = tid >> 6, l = tid & 63;
    const int lane_m = l & 15, quad = l >> 4;
    const int bh = blockIdx.y;
    const int xm = (blockIdx.x & 1) ? (15 - (blockIdx.x >> 1)) : (blockIdx.x >> 1);
    const int q0 = xm * 128;
    const int qw0 = q0 + w * 32;
    const u16* qp = Qg + (size_t)bh * S_ * 64;
    const u16* kp = Kg + (size_t)bh * S_ * 64;
    const u16* vp = Vg + (size_t)bh * S_ * 64;

    shortx8 qF[2][2];
#pragma unroll
    for (int nb = 0; nb < 2; nb++)
#pragma unroll
        for (int ks = 0; ks < 2; ks++)
            qF[nb][ks] = *(const shortx8*)(qp + (size_t)(qw0 + nb * 16 + lane_m) * 64 +
                                           ks * 32 + quad * 8);

    floatx4 o_acc[4][2];
#pragma unroll
    for (int md = 0; md < 4; md++)
#pragma unroll
        for (int nb = 0; nb < 2; nb++) o_acc[md][nb] = (floatx4){0.f, 0.f, 0.f, 0.f};
    float m_i[2] = {-1e30f, -1e30f}, l_i[2] = {0.f, 0.f};

    const int ntiles = (q0 >> 6) + 2;
    const int myend = qw0 + 31;
    const int i0 = tid, i1 = tid + 256;
    u16* psw = &Ps[w][0];

    // K staging geometry: 1KB/wave-call = 8 rows; lane -> (row lr8, slot sl8)
    const int lr8 = l >> 3, sl8 = l & 7;
    const int cK = sl8 ^ (lr8 & 7);  // logical chunk landing in slot sl8
    const int rbK0 = w * 8, rbK1 = 32 + w * 8;
    const u16* Krow0 = kp + (size_t)(rbK0 + lr8) * 64 + cK * 8;
    const u16* Krow1 = kp + (size_t)(rbK1 + lr8) * 64 + cK * 8;

    for (int t = 0; t < ntiles; t++) {
        const int k0 = t * 64;
        // V into registers (pre-barrier ok)
        const int c2a = i0 >> 6, r2a = i0 & 63;
        const int c2b = i1 >> 6, r2b = i1 & 63;
        uint4 vv0 = *(const uint4*)(vp + (size_t)(k0 + r2a) * 64 + c2a * 8);
        uint4 vv1 = *(const uint4*)(vp + (size_t)(k0 + r2b) * 64 + c2b * 8);
        __syncthreads();  // prior tile's LDS reads complete
        glds16(Krow0 + (size_t)k0 * 64, Ks + rbK0 * 64);
        glds16(Krow1 + (size_t)k0 * 64, Ks + rbK1 * 64);
        {
            const u16* pv = (const u16*)&vv0;
#pragma unroll
            for (int j = 0; j < 8; j++) Vt[(c2a * 8 + j) * 72 + r2a] = pv[j];
            pv = (const u16*)&vv1;
#pragma unroll
            for (int j = 0; j < 8; j++) Vt[(c2b * 8 + j) * 72 + r2b] = pv[j];
        }
        __syncthreads();  // drains vm (K DMA) + lgkm (V writes)

        if (k0 <= myend) {  // wave-uniform: skip fully-masked tiles
            // ---- S^T = K * Q^T ----
            floatx4 sc[4][2];
#pragma unroll
            for (int mb = 0; mb < 4; mb++)
#pragma unroll
                for (int nb = 0; nb < 2; nb++) sc[mb][nb] = (floatx4){0.f, 0.f, 0.f, 0.f};
#pragma unroll
            for (int ks = 0; ks < 2; ks++) {
                shortx8 kA[4];
#pragma unroll
                for (int mb = 0; mb < 4; mb++) {
                    const int r = mb * 16 + lane_m;
                    kA[mb] = *(const shortx8*)(Ks + r * 64 + (((ks * 4 + quad) ^ (r & 7)) * 8));
                }
#pragma unroll
                for (int mb = 0; mb < 4; mb++)
#pragma unroll
                    for (int nb = 0; nb < 2; nb++)
                        sc[mb][nb] = __builtin_amdgcn_mfma_f32_16x16x32_bf16(
                            kA[mb], qF[nb][ks], sc[mb][nb], 0, 0, 0);
            }

            const bool maskedTile = (k0 + 63 > qw0);
#pragma unroll
            for (int nb = 0; nb < 2; nb++) {
                const int qg = qw0 + nb * 16 + lane_m;
                if (maskedTile) {
#pragma unroll
                    for (int mb = 0; mb < 4; mb++)
#pragma unroll
                        for (int r = 0; r < 4; r++) {
                            const int kvg = k0 + mb * 16 + quad * 4 + r;
                            if (kvg > qg) sc[mb][nb][r] = -1e30f;
                        }
                }
                float mloc = -1e30f;
#pragma unroll
                for (int mb = 0; mb < 4; mb++) {
                    float a = fmaxf(fmaxf(sc[mb][nb][0], sc[mb][nb][1]),
                                    fmaxf(sc[mb][nb][2], sc[mb][nb][3]));
                    mloc = fmaxf(mloc, a);
                }
                mloc = fmaxf(mloc, __shfl_xor(mloc, 16));
                mloc = fmaxf(mloc, __shfl_xor(mloc, 32));
                const float mnew = fmaxf(m_i[nb], mloc);
                const float alpha = __builtin_amdgcn_exp2f(m_i[nb] - mnew);
                m_i[nb] = mnew;
                float psum = 0.f;
#pragma unroll
                for (int mb = 0; mb < 4; mb++) {
                    const float p0 = __builtin_amdgcn_exp2f(sc[mb][nb][0] - mnew);
                    const float p1 = __builtin_amdgcn_exp2f(sc[mb][nb][1] - mnew);
                    const float p2 = __builtin_amdgcn_exp2f(sc[mb][nb][2] - mnew);
                    const float p3 = __builtin_amdgcn_exp2f(sc[mb][nb][3] - mnew);
                    psum += (p0 + p1) + (p2 + p3);
                    // P^T stored as [q][kv]: 4 consecutive kv -> one b64 write
                    *(unsigned long long*)(psw + (lane_m + 16 * nb) * 72 + mb * 16 + quad * 4) =
                        pack4(p0, p1, p2, p3);
                }
                psum += __shfl_xor(psum, 16);
                psum += __shfl_xor(psum, 32);
                l_i[nb] = l_i[nb] * alpha + psum;
#pragma unroll
                for (int md = 0; md < 4; md++) o_acc[md][nb] *= alpha;
            }
            // no barrier: Ps region is per-wave

            // ---- O^T += V^T * P^T ----
#pragma unroll
            for (int ks = 0; ks < 2; ks++) {
                shortx8 vF[4], pF[2];
#pragma unroll
                for (int md = 0; md < 4; md++)
                    vF[md] = *(const shortx8*)(Vt + (md * 16 + lane_m) * 72 + ks * 32 + quad * 8);
#pragma unroll
                for (int nb = 0; nb < 2; nb++)
                    pF[nb] = *(const shortx8*)(psw + (lane_m + 16 * nb) * 72 + ks * 32 + quad * 8);
#pragma unroll
                for (int md = 0; md < 4; md++)
#pragma unroll
                    for (int nb = 0; nb < 2; nb++)
                        o_acc[md][nb] = __builtin_amdgcn_mfma_f32_16x16x32_bf16(
                            vF[md], pF[nb], o_acc[md][nb], 0, 0, 0);
            }
        }
    }

    // ---- epilogue: O^T col=q=lane_m+16nb, row=d=16md+quad*4+r ----
    const int b = bh >> 4, h = bh & 15;
#pragma unroll
    for (int nb = 0; nb < 2; nb++) {
        const float inv = 1.0f / l_i[nb];
        const int qg = qw0 + nb * 16 + lane_m;
        const size_t base = ((size_t)b * 2048 + qg) * 1024 + h * 64;
#pragma unroll
        for (int md = 0; md < 4; md++) {
            *(unsigned long long*)(Og + base + md * 16 + quad * 4) =
                pack4(o_acc[md][nb][0] * inv, o_acc[md][nb][1] * inv,
                      o_acc[md][nb][2] * inv, o_acc[md][nb][3] * inv);
        }
    }
}

// ---------------------------------------------------------------------------
extern "C" void kernel_launch(void* const* d_in, const int* in_sizes, int n_in,
                              void* d_out, int out_size, void* d_ws, size_t ws_size,
                              hipStream_t stream) {
    const void* x      = d_in[0];
    const void* w_attn = d_in[2];
    const void* b_attn = d_in[3];
    const void* w_proj = d_in[4];
    const void* b_proj = d_in[5];

    u16* qws = (u16*)d_ws;                 // 8388608
    u16* kws = qws + 8388608;
    u16* vws = kws + 8388608;
    u16* xb  = vws + 8388608;              // x normalized to bf16
    u16* aws = xb;                         // attn output aliases xb
    u16* wtA = xb + 8388608;               // w_attn^T: 3072x1024
    u16* wtP = wtA + 3145728;              // w_proj^T: 1024x1024
    u16* bAb = wtP + 1048576;              // 3072
    u16* bPb = bAb + 3072;                 // 1024
    int* flag = (int*)(bPb + 1024);

    detect_dtype<<<1, 64, 0, stream>>>((const unsigned int*)x, flag);
    convert_x<<<4096, 256, 0, stream>>>(x, xb, flag);
    convert_bias<<<1, 256, 0, stream>>>(b_attn, b_proj, bAb, bPb, flag);
    transpose_any<<<dim3(3072 / 32, 1024 / 32), 256, 0, stream>>>(w_attn, wtA, 1024, 3072, flag);
    transpose_any<<<dim3(1024 / 32, 1024 / 32), 256, 0, stream>>>(w_proj, wtP, 1024, 1024, flag);

    gemm_bt<1><<<dim3(8192 / 128, 3072 / 128), 256, 0, stream>>>(
        xb, wtA, bAb, nullptr, 8192, 3072, 1024, qws, kws, vws, flag);

    attn_kernel<<<dim3(2048 / 128, B_ * H_), 256, 0, stream>>>(qws, kws, vws, aws);

    gemm_bt<0><<<dim3(8192 / 128, 1024 / 128), 256, 0, stream>>>(
        aws, wtP, bPb, d_out, 8192, 1024, 1024, nullptr, nullptr, nullptr, flag);
}

// Round 7
// 381.769 us; speedup vs baseline: 1.0292x; 1.0292x over previous
//
#include <hip/hip_runtime.h>

typedef unsigned short u16;
typedef __attribute__((ext_vector_type(4))) float floatx4;
typedef __attribute__((ext_vector_type(8))) short shortx8;

#define B_ 4
#define S_ 2048
#define D_ 1024
#define H_ 16
#define HD_ 64

__device__ __forceinline__ float b2f(u16 u) {
    return __uint_as_float(((unsigned int)u) << 16);
}
__device__ __forceinline__ u16 f2b(float f) {
    unsigned int u = __float_as_uint(f);
    u += 0x7fffu + ((u >> 16) & 1u);
    return (u16)(u >> 16);
}
__device__ __forceinline__ unsigned long long pack4(float a, float b, float c, float d) {
    return (unsigned long long)f2b(a) | ((unsigned long long)f2b(b) << 16) |
           ((unsigned long long)f2b(c) << 32) | ((unsigned long long)f2b(d) << 48);
}
// bf16x2 pack, round-half-up: (hi16(b+0x8000) << 16) | hi16(a+0x8000) via v_perm_b32
__device__ __forceinline__ unsigned int permpk(float a, float b) {
    return __builtin_amdgcn_perm(__float_as_uint(b) + 0x8000u,
                                 __float_as_uint(a) + 0x8000u, 0x07060302u);
}
// async global->LDS, 16B per lane; LDS dest = wave-uniform base + lane*16
__device__ __forceinline__ void glds16(const u16* g, u16* l) {
    __builtin_amdgcn_global_load_lds(
        (const __attribute__((address_space(1))) unsigned int*)g,
        (__attribute__((address_space(3))) unsigned int*)l, 16, 0, 0);
}

// ---------------------------------------------------------------------------
// Dtype detector: bf16 -> flag=1, fp32 -> flag=0.
// ---------------------------------------------------------------------------
__global__ void detect_dtype(const unsigned int* __restrict__ x, int* __restrict__ flag) {
    const int l = threadIdx.x;  // 64 threads
    int cnt = 0;
    for (int i = l; i < 4096; i += 64) {
        const unsigned int e = (x[i] >> 7) & 0xffu;
        cnt += (e >= 110u && e <= 134u) ? 1 : 0;
    }
#pragma unroll
    for (int d = 1; d < 64; d <<= 1) cnt += __shfl_xor(cnt, d);
    if (l == 0) *flag = (cnt > 2048) ? 1 : 0;
}

__global__ __launch_bounds__(256) void convert_x(const void* __restrict__ xin,
                                                 u16* __restrict__ xb,
                                                 const int* __restrict__ flag) {
    const int isbf = *flag;
    const size_t i = ((size_t)blockIdx.x * 256 + threadIdx.x) * 8;
    if (isbf) {
        *(uint4*)(xb + i) = *(const uint4*)((const u16*)xin + i);
    } else {
        const float* xf = (const float*)xin;
        float4 a = *(const float4*)(xf + i);
        float4 b = *(const float4*)(xf + i + 4);
        u16 o[8] = {f2b(a.x), f2b(a.y), f2b(a.z), f2b(a.w),
                    f2b(b.x), f2b(b.y), f2b(b.z), f2b(b.w)};
        *(uint4*)(xb + i) = *(uint4*)o;
    }
}

__global__ void convert_bias(const void* __restrict__ bA, const void* __restrict__ bP,
                             u16* __restrict__ bAb, u16* __restrict__ bPb,
                             const int* __restrict__ flag) {
    const int isbf = *flag;
    for (int i = threadIdx.x; i < 3072; i += 256)
        bAb[i] = isbf ? ((const u16*)bA)[i] : f2b(((const float*)bA)[i]);
    for (int i = threadIdx.x; i < 1024; i += 256)
        bPb[i] = isbf ? ((const u16*)bP)[i] : f2b(((const float*)bP)[i]);
}

// ---------------------------------------------------------------------------
// Transpose (+ dtype normalize): in[K][N] (bf16 or fp32) -> out[N][K] bf16.
// ---------------------------------------------------------------------------
__global__ __launch_bounds__(256) void transpose_any(const void* __restrict__ in,
                                                     u16* __restrict__ out,
                                                     int K, int N,
                                                     const int* __restrict__ flag) {
    const int isbf = *flag;
    __shared__ u16 tile[32][33];
    const int tx = threadIdx.x & 31;
    const int ty = threadIdx.x >> 5;
    const int bx = blockIdx.x * 32;  // N index
    const int by = blockIdx.y * 32;  // K index
    if (isbf) {
#pragma unroll
        for (int i = 0; i < 32; i += 8)
            tile[ty + i][tx] = ((const u16*)in)[(size_t)(by + ty + i) * N + bx + tx];
    } else {
#pragma unroll
        for (int i = 0; i < 32; i += 8)
            tile[ty + i][tx] = f2b(((const float*)in)[(size_t)(by + ty + i) * N + bx + tx]);
    }
    __syncthreads();
#pragma unroll
    for (int i = 0; i < 32; i += 8)
        out[(size_t)(bx + ty + i) * K + by + tx] = tile[tx][ty + i];
}

// ---------------------------------------------------------------------------
// C[M x N] = A[M x K] * BT[N x K]^T + bias.  bf16 in, fp32 accum.
// m97-style: global_load_lds width-16 staging, pitch-32 LDS with XOR chunk
// swizzle (slot = chunk ^ ((row>>1)&3)).
// MODE 0: store to out (bf16 or fp32 per flag).
// MODE 1: QKV scatter: Q (pre-scaled 0.125*log2e), K -> [bh][s][64];
//         V -> TRANSPOSED [bh][d][s] so attention can DMA V^T tiles.
// ---------------------------------------------------------------------------
template <int MODE>
__global__ __launch_bounds__(256) void gemm_bt(const u16* __restrict__ A,
                                               const u16* __restrict__ BT,
                                               const u16* __restrict__ bias,
                                               void* __restrict__ outv,
                                               int M, int N, int K,
                                               u16* __restrict__ qws,
                                               u16* __restrict__ kws,
                                               u16* __restrict__ vws,
                                               const int* __restrict__ flag) {
    __shared__ __align__(16) u16 As[128 * 32];
    __shared__ __align__(16) u16 Bs[128 * 32];

    const int isbf = (MODE == 0) ? *flag : 1;
    const int tid = threadIdx.x;
    const int w = tid >> 6, l = tid & 63;
    const int lane_m = l & 15, quad = l >> 4;
    const int bm = blockIdx.x * 128, bn = blockIdx.y * 128;
    const int wm = (w >> 1) * 64, wn = (w & 1) * 64;

    floatx4 acc[4][4];
#pragma unroll
    for (int i = 0; i < 4; i++)
#pragma unroll
        for (int j = 0; j < 4; j++) acc[i][j] = (floatx4){0.f, 0.f, 0.f, 0.f};

    // staging geometry: wave covers 16-row groups rb0, rb1; lane -> (row, slot)
    const int lr = l >> 2, sl = l & 3;
    const int cA = sl ^ ((lr >> 1) & 3);  // logical chunk that lands in slot sl
    const int rb0 = w * 16, rb1 = 64 + w * 16;
    const u16* Arow0 = A + (size_t)(bm + rb0 + lr) * K + cA * 8;
    const u16* Arow1 = A + (size_t)(bm + rb1 + lr) * K + cA * 8;
    const u16* Brow0 = BT + (size_t)(bn + rb0 + lr) * K + cA * 8;
    const u16* Brow1 = BT + (size_t)(bn + rb1 + lr) * K + cA * 8;

    for (int k0 = 0; k0 < K; k0 += 32) {
        __syncthreads();  // prior iteration's frag reads complete
        glds16(Arow0 + k0, As + rb0 * 32);
        glds16(Arow1 + k0, As + rb1 * 32);
        glds16(Brow0 + k0, Bs + rb0 * 32);
        glds16(Brow1 + k0, Bs + rb1 * 32);
        __syncthreads();  // vmcnt(0) drain: tiles resident

        shortx8 af[4], bf[4];
#pragma unroll
        for (int mb = 0; mb < 4; mb++) {
            const int r = wm + mb * 16 + lane_m;
            af[mb] = *(const shortx8*)(As + r * 32 + (quad ^ ((r >> 1) & 3)) * 8);
        }
#pragma unroll
        for (int nb = 0; nb < 4; nb++) {
            const int r = wn + nb * 16 + lane_m;
            bf[nb] = *(const shortx8*)(Bs + r * 32 + (quad ^ ((r >> 1) & 3)) * 8);
        }
#pragma unroll
        for (int mb = 0; mb < 4; mb++)
#pragma unroll
            for (int nb = 0; nb < 4; nb++)
                acc[mb][nb] = __builtin_amdgcn_mfma_f32_16x16x32_bf16(
                    af[mb], bf[nb], acc[mb][nb], 0, 0, 0);
    }

    const float SCALE_Q = 0.18033688011112042f;  // 0.125 * log2(e)
#pragma unroll
    for (int nb = 0; nb < 4; nb++) {
        const int col = bn + wn + nb * 16 + lane_m;
        const float bv = b2f(bias[col]);
#pragma unroll
        for (int mb = 0; mb < 4; mb++) {
            const int rowb = bm + wm + mb * 16 + quad * 4;
#pragma unroll
            for (int r = 0; r < 4; r++) {
                float v = acc[mb][nb][r] + bv;
                const int rr = rowb + r;
                if (MODE == 0) {
                    if (isbf) ((u16*)outv)[(size_t)rr * N + col] = f2b(v);
                    else ((float*)outv)[(size_t)rr * N + col] = v;
                } else {
                    const int which = col >> 10;  // uniform per block
                    if (which == 0) v *= SCALE_Q;
                    const int h = (col >> 6) & 15;
                    const int hd = col & 63;
                    const int b = rr >> 11, s = rr & 2047;
                    if (which == 2) {
                        // V transposed: [bh][d][s]
                        vws[((size_t)(b * 16 + h) * 64 + hd) * 2048 + s] = f2b(v);
                    } else {
                        u16* dst = which == 0 ? qws : kws;
                        dst[((size_t)(b * 16 + h) * 2048 + s) * 64 + hd] = f2b(v);
                    }
                }
            }
        }
    }
}

// ---------------------------------------------------------------------------
// Flash attention, causal, transposed-score scheme, DMA-pipelined.
// S^T = K*Q^T (col=q,row=kv) -> in-register softmax; O^T = V^T*P^T.
// K [bh][s][64] and V^T [bh][d][s] tiles both staged via global_load_lds into
// double buffers (slot = chunk ^ (row&7) swizzle); DMA for tile t+1 issues
// before compute of tile t, so the barrier's vmcnt(0) drain is hidden.
// Block = 256 threads (4 waves); BQ=128 (32 q/wave); BKV=64.
// ---------------------------------------------------------------------------
__global__ __launch_bounds__(256) void attn_kernel(const u16* __restrict__ Qg,
                                                   const u16* __restrict__ Kg,
                                                   const u16* __restrict__ Vtg,
                                                   u16* __restrict__ Og) {
    __shared__ __align__(16) u16 Ks[2][64 * 64];  // K tile [kv][d], swizzled
    __shared__ __align__(16) u16 Vs[2][64 * 64];  // V^T tile [d][kv], swizzled
    __shared__ __align__(16) u16 Ps[4][32 * 72];  // per-wave P^T as [q][kv]

    const int tid = threadIdx.x, w = tid >> 6, l = tid & 63;
    const int lane_m = l & 15, quad = l >> 4;
    const int bh = blockIdx.y;
    const int xm = (blockIdx.x & 1) ? (15 - (blockIdx.x >> 1)) : (blockIdx.x >> 1);
    const int q0 = xm * 128;
    const int qw0 = q0 + w * 32;
    const u16* qp = Qg + (size_t)bh * S_ * 64;
    const u16* kp = Kg + (size_t)bh * S_ * 64;
    const u16* vtp = Vtg + (size_t)bh * 64 * S_;

    shortx8 qF[2][2];
#pragma unroll
    for (int nb = 0; nb < 2; nb++)
#pragma unroll
        for (int ks = 0; ks < 2; ks++)
            qF[nb][ks] = *(const shortx8*)(qp + (size_t)(qw0 + nb * 16 + lane_m) * 64 +
                                           ks * 32 + quad * 8);

    floatx4 o_acc[4][2];
#pragma unroll
    for (int md = 0; md < 4; md++)
#pragma unroll
        for (int nb = 0; nb < 2; nb++) o_acc[md][nb] = (floatx4){0.f, 0.f, 0.f, 0.f};
    float m_i[2] = {-1e30f, -1e30f}, l_i[2] = {0.f, 0.f};

    const int ntiles = (q0 >> 6) + 2;
    const int myend = qw0 + 31;
    u16* psw = &Ps[w][0];

    // staging geometry: 8 rows per wave-call; lane -> (row lr8, slot sl8)
    const int lr8 = l >> 3, sl8 = l & 7;
    const int cK = sl8 ^ (lr8 & 7);  // logical chunk landing in slot sl8
    const int rb0 = w * 8, rb1 = 32 + w * 8;
    const u16* Kr0 = kp + (size_t)(rb0 + lr8) * 64 + cK * 8;
    const u16* Kr1 = kp + (size_t)(rb1 + lr8) * 64 + cK * 8;
    const u16* Vr0 = vtp + (size_t)(rb0 + lr8) * S_ + cK * 8;  // rows = d
    const u16* Vr1 = vtp + (size_t)(rb1 + lr8) * S_ + cK * 8;

    auto stage = [&](int t) {
        const int k0 = t * 64;
        u16* kd = &Ks[t & 1][0];
        u16* vd = &Vs[t & 1][0];
        glds16(Kr0 + (size_t)k0 * 64, kd + rb0 * 64);
        glds16(Kr1 + (size_t)k0 * 64, kd + rb1 * 64);
        glds16(Vr0 + k0, vd + rb0 * 64);
        glds16(Vr1 + k0, vd + rb1 * 64);
    };

    stage(0);
    for (int t = 0; t < ntiles; t++) {
        const int k0 = t * 64;
        __syncthreads();  // buf[t&1] DMA drained; all reads of buf[(t+1)&1] done
        if (t + 1 < ntiles) stage(t + 1);

        if (k0 <= myend) {  // wave-uniform: skip fully-masked tiles
            const u16* kb = &Ks[t & 1][0];
            const u16* vb = &Vs[t & 1][0];
            // ---- S^T = K * Q^T ----
            floatx4 sc[4][2];
#pragma unroll
            for (int mb = 0; mb < 4; mb++)
#pragma unroll
                for (int nb = 0; nb < 2; nb++) sc[mb][nb] = (floatx4){0.f, 0.f, 0.f, 0.f};
#pragma unroll
            for (int ks = 0; ks < 2; ks++) {
                shortx8 kA[4];
#pragma unroll
                for (int mb = 0; mb < 4; mb++) {
                    const int r = mb * 16 + lane_m;
                    kA[mb] = *(const shortx8*)(kb + r * 64 + (((ks * 4 + quad) ^ (r & 7)) * 8));
                }
#pragma unroll
                for (int mb = 0; mb < 4; mb++)
#pragma unroll
                    for (int nb = 0; nb < 2; nb++)
                        sc[mb][nb] = __builtin_amdgcn_mfma_f32_16x16x32_bf16(
                            kA[mb], qF[nb][ks], sc[mb][nb], 0, 0, 0);
            }

            const bool maskedTile = (k0 + 63 > qw0);
#pragma unroll
            for (int nb = 0; nb < 2; nb++) {
                const int qg = qw0 + nb * 16 + lane_m;
                if (maskedTile) {
#pragma unroll
                    for (int mb = 0; mb < 4; mb++)
#pragma unroll
                        for (int r = 0; r < 4; r++) {
                            const int kvg = k0 + mb * 16 + quad * 4 + r;
                            if (kvg > qg) sc[mb][nb][r] = -1e30f;
                        }
                }
                float mloc = -1e30f;
#pragma unroll
                for (int mb = 0; mb < 4; mb++) {
                    float a = fmaxf(fmaxf(sc[mb][nb][0], sc[mb][nb][1]),
                                    fmaxf(sc[mb][nb][2], sc[mb][nb][3]));
                    mloc = fmaxf(mloc, a);
                }
                mloc = fmaxf(mloc, __shfl_xor(mloc, 16));
                mloc = fmaxf(mloc, __shfl_xor(mloc, 32));
                const float mnew = fmaxf(m_i[nb], mloc);
                const float alpha = __builtin_amdgcn_exp2f(m_i[nb] - mnew);
                m_i[nb] = mnew;
                float psum = 0.f;
#pragma unroll
                for (int mb = 0; mb < 4; mb++) {
                    const float p0 = __builtin_amdgcn_exp2f(sc[mb][nb][0] - mnew);
                    const float p1 = __builtin_amdgcn_exp2f(sc[mb][nb][1] - mnew);
                    const float p2 = __builtin_amdgcn_exp2f(sc[mb][nb][2] - mnew);
                    const float p3 = __builtin_amdgcn_exp2f(sc[mb][nb][3] - mnew);
                    psum += (p0 + p1) + (p2 + p3);
                    // P^T [q][kv]: 4 consecutive kv -> one 8B write (perm pack)
                    uint2 pk = {permpk(p0, p1), permpk(p2, p3)};
                    *(uint2*)(psw + (lane_m + 16 * nb) * 72 + mb * 16 + quad * 4) = pk;
                }
                psum += __shfl_xor(psum, 16);
                psum += __shfl_xor(psum, 32);
                l_i[nb] = l_i[nb] * alpha + psum;
#pragma unroll
                for (int md = 0; md < 4; md++) o_acc[md][nb] *= alpha;
            }
            // no barrier: Ps region is per-wave

            // ---- O^T += V^T * P^T ----
#pragma unroll
            for (int ks = 0; ks < 2; ks++) {
                shortx8 vF[4], pF[2];
#pragma unroll
                for (int md = 0; md < 4; md++) {
                    const int r = md * 16 + lane_m;
                    vF[md] = *(const shortx8*)(vb + r * 64 + (((ks * 4 + quad) ^ (r & 7)) * 8));
                }
#pragma unroll
                for (int nb = 0; nb < 2; nb++)
                    pF[nb] = *(const shortx8*)(psw + (lane_m + 16 * nb) * 72 + ks * 32 + quad * 8);
#pragma unroll
                for (int md = 0; md < 4; md++)
#pragma unroll
                    for (int nb = 0; nb < 2; nb++)
                        o_acc[md][nb] = __builtin_amdgcn_mfma_f32_16x16x32_bf16(
                            vF[md], pF[nb], o_acc[md][nb], 0, 0, 0);
            }
        }
    }

    // ---- epilogue: O^T col=q=lane_m+16nb, row=d=16md+quad*4+r ----
    const int b = bh >> 4, h = bh & 15;
#pragma unroll
    for (int nb = 0; nb < 2; nb++) {
        const float inv = 1.0f / l_i[nb];
        const int qg = qw0 + nb * 16 + lane_m;
        const size_t base = ((size_t)b * 2048 + qg) * 1024 + h * 64;
#pragma unroll
        for (int md = 0; md < 4; md++) {
            *(unsigned long long*)(Og + base + md * 16 + quad * 4) =
                pack4(o_acc[md][nb][0] * inv, o_acc[md][nb][1] * inv,
                      o_acc[md][nb][2] * inv, o_acc[md][nb][3] * inv);
        }
    }
}

// ---------------------------------------------------------------------------
extern "C" void kernel_launch(void* const* d_in, const int* in_sizes, int n_in,
                              void* d_out, int out_size, void* d_ws, size_t ws_size,
                              hipStream_t stream) {
    const void* x      = d_in[0];
    const void* w_attn = d_in[2];
    const void* b_attn = d_in[3];
    const void* w_proj = d_in[4];
    const void* b_proj = d_in[5];

    u16* qws = (u16*)d_ws;                 // 8388608
    u16* kws = qws + 8388608;
    u16* vws = kws + 8388608;              // holds V^T [bh][d][s]
    u16* xb  = vws + 8388608;              // x normalized to bf16
    u16* aws = xb;                         // attn output aliases xb
    u16* wtA = xb + 8388608;               // w_attn^T: 3072x1024
    u16* wtP = wtA + 3145728;              // w_proj^T: 1024x1024
    u16* bAb = wtP + 1048576;              // 3072
    u16* bPb = bAb + 3072;                 // 1024
    int* flag = (int*)(bPb + 1024);

    detect_dtype<<<1, 64, 0, stream>>>((const unsigned int*)x, flag);
    convert_x<<<4096, 256, 0, stream>>>(x, xb, flag);
    convert_bias<<<1, 256, 0, stream>>>(b_attn, b_proj, bAb, bPb, flag);
    transpose_any<<<dim3(3072 / 32, 1024 / 32), 256, 0, stream>>>(w_attn, wtA, 1024, 3072, flag);
    transpose_any<<<dim3(1024 / 32, 1024 / 32), 256, 0, stream>>>(w_proj, wtP, 1024, 1024, flag);

    gemm_bt<1><<<dim3(8192 / 128, 3072 / 128), 256, 0, stream>>>(
        xb, wtA, bAb, nullptr, 8192, 3072, 1024, qws, kws, vws, flag);

    attn_kernel<<<dim3(2048 / 128, B_ * H_), 256, 0, stream>>>(qws, kws, vws, aws);

    gemm_bt<0><<<dim3(8192 / 128, 1024 / 128), 256, 0, stream>>>(
        aws, wtP, bPb, d_out, 8192, 1024, 1024, nullptr, nullptr, nullptr, flag);
}

// Round 8
// 328.476 us; speedup vs baseline: 1.1961x; 1.1622x over previous
//
#include <hip/hip_runtime.h>

typedef unsigned short u16;
typedef __attribute__((ext_vector_type(4))) float floatx4;
typedef __attribute__((ext_vector_type(8))) short shortx8;

#define B_ 4
#define S_ 2048
#define D_ 1024
#define H_ 16
#define HD_ 64

__device__ __forceinline__ float b2f(u16 u) {
    return __uint_as_float(((unsigned int)u) << 16);
}
__device__ __forceinline__ u16 f2b(float f) {
    unsigned int u = __float_as_uint(f);
    u += 0x7fffu + ((u >> 16) & 1u);
    return (u16)(u >> 16);
}
__device__ __forceinline__ unsigned long long pack4(float a, float b, float c, float d) {
    return (unsigned long long)f2b(a) | ((unsigned long long)f2b(b) << 16) |
           ((unsigned long long)f2b(c) << 32) | ((unsigned long long)f2b(d) << 48);
}
// bf16x2 pack, round-half-up: (hi16(b+0x8000) << 16) | hi16(a+0x8000) via v_perm_b32
__device__ __forceinline__ unsigned int permpk(float a, float b) {
    return __builtin_amdgcn_perm(__float_as_uint(b) + 0x8000u,
                                 __float_as_uint(a) + 0x8000u, 0x07060302u);
}
// async global->LDS, 16B per lane; LDS dest = wave-uniform base + lane*16
__device__ __forceinline__ void glds16(const u16* g, u16* l) {
    __builtin_amdgcn_global_load_lds(
        (const __attribute__((address_space(1))) unsigned int*)g,
        (__attribute__((address_space(3))) unsigned int*)l, 16, 0, 0);
}

// ---------------------------------------------------------------------------
// Dtype detector: bf16 -> flag=1, fp32 -> flag=0.
// ---------------------------------------------------------------------------
__global__ void detect_dtype(const unsigned int* __restrict__ x, int* __restrict__ flag) {
    const int l = threadIdx.x;  // 64 threads
    int cnt = 0;
    for (int i = l; i < 4096; i += 64) {
        const unsigned int e = (x[i] >> 7) & 0xffu;
        cnt += (e >= 110u && e <= 134u) ? 1 : 0;
    }
#pragma unroll
    for (int d = 1; d < 64; d <<= 1) cnt += __shfl_xor(cnt, d);
    if (l == 0) *flag = (cnt > 2048) ? 1 : 0;
}

__global__ __launch_bounds__(256) void convert_x(const void* __restrict__ xin,
                                                 u16* __restrict__ xb,
                                                 const int* __restrict__ flag) {
    const int isbf = *flag;
    const size_t i = ((size_t)blockIdx.x * 256 + threadIdx.x) * 8;
    if (isbf) {
        *(uint4*)(xb + i) = *(const uint4*)((const u16*)xin + i);
    } else {
        const float* xf = (const float*)xin;
        float4 a = *(const float4*)(xf + i);
        float4 b = *(const float4*)(xf + i + 4);
        u16 o[8] = {f2b(a.x), f2b(a.y), f2b(a.z), f2b(a.w),
                    f2b(b.x), f2b(b.y), f2b(b.z), f2b(b.w)};
        *(uint4*)(xb + i) = *(uint4*)o;
    }
}

__global__ void convert_bias(const void* __restrict__ bA, const void* __restrict__ bP,
                             u16* __restrict__ bAb, u16* __restrict__ bPb,
                             const int* __restrict__ flag) {
    const int isbf = *flag;
    for (int i = threadIdx.x; i < 3072; i += 256)
        bAb[i] = isbf ? ((const u16*)bA)[i] : f2b(((const float*)bA)[i]);
    for (int i = threadIdx.x; i < 1024; i += 256)
        bPb[i] = isbf ? ((const u16*)bP)[i] : f2b(((const float*)bP)[i]);
}

// ---------------------------------------------------------------------------
// Transpose (+ dtype normalize): in[K][N] (bf16 or fp32) -> out[N][K] bf16.
// ---------------------------------------------------------------------------
__global__ __launch_bounds__(256) void transpose_any(const void* __restrict__ in,
                                                     u16* __restrict__ out,
                                                     int K, int N,
                                                     const int* __restrict__ flag) {
    const int isbf = *flag;
    __shared__ u16 tile[32][33];
    const int tx = threadIdx.x & 31;
    const int ty = threadIdx.x >> 5;
    const int bx = blockIdx.x * 32;  // N index
    const int by = blockIdx.y * 32;  // K index
    if (isbf) {
#pragma unroll
        for (int i = 0; i < 32; i += 8)
            tile[ty + i][tx] = ((const u16*)in)[(size_t)(by + ty + i) * N + bx + tx];
    } else {
#pragma unroll
        for (int i = 0; i < 32; i += 8)
            tile[ty + i][tx] = f2b(((const float*)in)[(size_t)(by + ty + i) * N + bx + tx]);
    }
    __syncthreads();
#pragma unroll
    for (int i = 0; i < 32; i += 8)
        out[(size_t)(bx + ty + i) * K + by + tx] = tile[tx][ty + i];
}

// ---------------------------------------------------------------------------
// C[M x N] = A[M x K] * BT[N x K]^T + bias.  bf16 in, fp32 accum.
// m97-style: global_load_lds width-16 staging, pitch-32 LDS with XOR chunk
// swizzle (slot = chunk ^ ((row>>1)&3)).
// MODE 0: store to out (bf16 or fp32 per flag).
// MODE 1: QKV scatter: Q (pre-scaled 0.125*log2e), K -> [bh][s][64];
//         V -> TRANSPOSED [bh][d][s] so attention can DMA V^T tiles.
// ---------------------------------------------------------------------------
template <int MODE>
__global__ __launch_bounds__(256) void gemm_bt(const u16* __restrict__ A,
                                               const u16* __restrict__ BT,
                                               const u16* __restrict__ bias,
                                               void* __restrict__ outv,
                                               int M, int N, int K,
                                               u16* __restrict__ qws,
                                               u16* __restrict__ kws,
                                               u16* __restrict__ vws,
                                               const int* __restrict__ flag) {
    __shared__ __align__(16) u16 As[128 * 32];
    __shared__ __align__(16) u16 Bs[128 * 32];

    const int isbf = (MODE == 0) ? *flag : 1;
    const int tid = threadIdx.x;
    const int w = tid >> 6, l = tid & 63;
    const int lane_m = l & 15, quad = l >> 4;
    const int bm = blockIdx.x * 128, bn = blockIdx.y * 128;
    const int wm = (w >> 1) * 64, wn = (w & 1) * 64;

    floatx4 acc[4][4];
#pragma unroll
    for (int i = 0; i < 4; i++)
#pragma unroll
        for (int j = 0; j < 4; j++) acc[i][j] = (floatx4){0.f, 0.f, 0.f, 0.f};

    // staging geometry: wave covers 16-row groups rb0, rb1; lane -> (row, slot)
    const int lr = l >> 2, sl = l & 3;
    const int cA = sl ^ ((lr >> 1) & 3);  // logical chunk that lands in slot sl
    const int rb0 = w * 16, rb1 = 64 + w * 16;
    const u16* Arow0 = A + (size_t)(bm + rb0 + lr) * K + cA * 8;
    const u16* Arow1 = A + (size_t)(bm + rb1 + lr) * K + cA * 8;
    const u16* Brow0 = BT + (size_t)(bn + rb0 + lr) * K + cA * 8;
    const u16* Brow1 = BT + (size_t)(bn + rb1 + lr) * K + cA * 8;

    for (int k0 = 0; k0 < K; k0 += 32) {
        __syncthreads();  // prior iteration's frag reads complete
        glds16(Arow0 + k0, As + rb0 * 32);
        glds16(Arow1 + k0, As + rb1 * 32);
        glds16(Brow0 + k0, Bs + rb0 * 32);
        glds16(Brow1 + k0, Bs + rb1 * 32);
        __syncthreads();  // vmcnt(0) drain: tiles resident

        shortx8 af[4], bf[4];
#pragma unroll
        for (int mb = 0; mb < 4; mb++) {
            const int r = wm + mb * 16 + lane_m;
            af[mb] = *(const shortx8*)(As + r * 32 + (quad ^ ((r >> 1) & 3)) * 8);
        }
#pragma unroll
        for (int nb = 0; nb < 4; nb++) {
            const int r = wn + nb * 16 + lane_m;
            bf[nb] = *(const shortx8*)(Bs + r * 32 + (quad ^ ((r >> 1) & 3)) * 8);
        }
#pragma unroll
        for (int mb = 0; mb < 4; mb++)
#pragma unroll
            for (int nb = 0; nb < 4; nb++)
                acc[mb][nb] = __builtin_amdgcn_mfma_f32_16x16x32_bf16(
                    af[mb], bf[nb], acc[mb][nb], 0, 0, 0);
    }

    const float SCALE_Q = 0.18033688011112042f;  // 0.125 * log2(e)
#pragma unroll
    for (int nb = 0; nb < 4; nb++) {
        const int col = bn + wn + nb * 16 + lane_m;
        const float bv = b2f(bias[col]);
#pragma unroll
        for (int mb = 0; mb < 4; mb++) {
            const int rowb = bm + wm + mb * 16 + quad * 4;
#pragma unroll
            for (int r = 0; r < 4; r++) {
                float v = acc[mb][nb][r] + bv;
                const int rr = rowb + r;
                if (MODE == 0) {
                    if (isbf) ((u16*)outv)[(size_t)rr * N + col] = f2b(v);
                    else ((float*)outv)[(size_t)rr * N + col] = v;
                } else {
                    const int which = col >> 10;  // uniform per block
                    if (which == 0) v *= SCALE_Q;
                    const int h = (col >> 6) & 15;
                    const int hd = col & 63;
                    const int b = rr >> 11, s = rr & 2047;
                    if (which == 2) {
                        // V transposed: [bh][d][s]
                        vws[((size_t)(b * 16 + h) * 64 + hd) * 2048 + s] = f2b(v);
                    } else {
                        u16* dst = which == 0 ? qws : kws;
                        dst[((size_t)(b * 16 + h) * 2048 + s) * 64 + hd] = f2b(v);
                    }
                }
            }
        }
    }
}

// ---------------------------------------------------------------------------
// Flash attention, causal, transposed-score scheme, DMA-pipelined,
// WORK-BALANCED: each block runs q-tile xm=blockIdx.x then 15-blockIdx.x.
// ntiles sum = (2xm+2)+(32-2xm) = 34 for EVERY block; grid (8,64) = 512
// blocks = exactly 2/CU, all resident -> static zero-tail schedule.
// S^T = K*Q^T (col=q,row=kv) -> in-register softmax; O^T = V^T*P^T.
// ---------------------------------------------------------------------------
__global__ __launch_bounds__(256) void attn_kernel(const u16* __restrict__ Qg,
                                                   const u16* __restrict__ Kg,
                                                   const u16* __restrict__ Vtg,
                                                   u16* __restrict__ Og) {
    __shared__ __align__(16) u16 Ks[2][64 * 64];  // K tile [kv][d], swizzled
    __shared__ __align__(16) u16 Vs[2][64 * 64];  // V^T tile [d][kv], swizzled
    __shared__ __align__(16) u16 Ps[4][32 * 72];  // per-wave P^T as [q][kv]

    const int tid = threadIdx.x, w = tid >> 6, l = tid & 63;
    const int lane_m = l & 15, quad = l >> 4;
    const int bh = blockIdx.y;
    const u16* qp = Qg + (size_t)bh * S_ * 64;
    const u16* kp = Kg + (size_t)bh * S_ * 64;
    const u16* vtp = Vtg + (size_t)bh * 64 * S_;
    u16* psw = &Ps[w][0];
    const int b = bh >> 4, h = bh & 15;

    // staging geometry: 8 rows per wave-call; lane -> (row lr8, slot sl8)
    const int lr8 = l >> 3, sl8 = l & 7;
    const int cK = sl8 ^ (lr8 & 7);  // logical chunk landing in slot sl8
    const int rb0 = w * 8, rb1 = 32 + w * 8;
    const u16* Kr0 = kp + (size_t)(rb0 + lr8) * 64 + cK * 8;
    const u16* Kr1 = kp + (size_t)(rb1 + lr8) * 64 + cK * 8;
    const u16* Vr0 = vtp + (size_t)(rb0 + lr8) * S_ + cK * 8;  // rows = d
    const u16* Vr1 = vtp + (size_t)(rb1 + lr8) * S_ + cK * 8;

    auto stage = [&](int t) {
        const int k0 = t * 64;
        u16* kd = &Ks[t & 1][0];
        u16* vd = &Vs[t & 1][0];
        glds16(Kr0 + (size_t)k0 * 64, kd + rb0 * 64);
        glds16(Kr1 + (size_t)k0 * 64, kd + rb1 * 64);
        glds16(Vr0 + k0, vd + rb0 * 64);
        glds16(Vr1 + k0, vd + rb1 * 64);
    };

    for (int pass = 0; pass < 2; pass++) {
        const int xm = pass ? (15 - (int)blockIdx.x) : (int)blockIdx.x;
        const int q0 = xm * 128;
        const int qw0 = q0 + w * 32;

        shortx8 qF[2][2];
#pragma unroll
        for (int nb = 0; nb < 2; nb++)
#pragma unroll
            for (int ks = 0; ks < 2; ks++)
                qF[nb][ks] = *(const shortx8*)(qp + (size_t)(qw0 + nb * 16 + lane_m) * 64 +
                                               ks * 32 + quad * 8);

        floatx4 o_acc[4][2];
#pragma unroll
        for (int md = 0; md < 4; md++)
#pragma unroll
            for (int nb = 0; nb < 2; nb++) o_acc[md][nb] = (floatx4){0.f, 0.f, 0.f, 0.f};
        float m_i[2] = {-1e30f, -1e30f}, l_i[2] = {0.f, 0.f};

        const int ntiles = (q0 >> 6) + 2;
        const int myend = qw0 + 31;

        __syncthreads();  // pass seam: prior pass's LDS reads complete
        stage(0);
        for (int t = 0; t < ntiles; t++) {
            const int k0 = t * 64;
            __syncthreads();  // buf[t&1] DMA drained; reads of buf[(t+1)&1] done
            if (t + 1 < ntiles) stage(t + 1);

            if (k0 <= myend) {  // wave-uniform: skip fully-masked tiles
                const u16* kb = &Ks[t & 1][0];
                const u16* vb = &Vs[t & 1][0];
                // ---- S^T = K * Q^T ----
                floatx4 sc[4][2];
#pragma unroll
                for (int mb = 0; mb < 4; mb++)
#pragma unroll
                    for (int nb = 0; nb < 2; nb++) sc[mb][nb] = (floatx4){0.f, 0.f, 0.f, 0.f};
#pragma unroll
                for (int ks = 0; ks < 2; ks++) {
                    shortx8 kA[4];
#pragma unroll
                    for (int mb = 0; mb < 4; mb++) {
                        const int r = mb * 16 + lane_m;
                        kA[mb] = *(const shortx8*)(kb + r * 64 + (((ks * 4 + quad) ^ (r & 7)) * 8));
                    }
#pragma unroll
                    for (int mb = 0; mb < 4; mb++)
#pragma unroll
                        for (int nb = 0; nb < 2; nb++)
                            sc[mb][nb] = __builtin_amdgcn_mfma_f32_16x16x32_bf16(
                                kA[mb], qF[nb][ks], sc[mb][nb], 0, 0, 0);
                }

                const bool maskedTile = (k0 + 63 > qw0);
#pragma unroll
                for (int nb = 0; nb < 2; nb++) {
                    const int qg = qw0 + nb * 16 + lane_m;
                    if (maskedTile) {
#pragma unroll
                        for (int mb = 0; mb < 4; mb++)
#pragma unroll
                            for (int r = 0; r < 4; r++) {
                                const int kvg = k0 + mb * 16 + quad * 4 + r;
                                if (kvg > qg) sc[mb][nb][r] = -1e30f;
                            }
                    }
                    float mloc = -1e30f;
#pragma unroll
                    for (int mb = 0; mb < 4; mb++) {
                        float a = fmaxf(fmaxf(sc[mb][nb][0], sc[mb][nb][1]),
                                        fmaxf(sc[mb][nb][2], sc[mb][nb][3]));
                        mloc = fmaxf(mloc, a);
                    }
                    mloc = fmaxf(mloc, __shfl_xor(mloc, 16));
                    mloc = fmaxf(mloc, __shfl_xor(mloc, 32));
                    const float mnew = fmaxf(m_i[nb], mloc);
                    const float alpha = __builtin_amdgcn_exp2f(m_i[nb] - mnew);
                    m_i[nb] = mnew;
                    float psum = 0.f;
#pragma unroll
                    for (int mb = 0; mb < 4; mb++) {
                        const float p0 = __builtin_amdgcn_exp2f(sc[mb][nb][0] - mnew);
                        const float p1 = __builtin_amdgcn_exp2f(sc[mb][nb][1] - mnew);
                        const float p2 = __builtin_amdgcn_exp2f(sc[mb][nb][2] - mnew);
                        const float p3 = __builtin_amdgcn_exp2f(sc[mb][nb][3] - mnew);
                        psum += (p0 + p1) + (p2 + p3);
                        // P^T [q][kv]: 4 consecutive kv -> one 8B write (perm pack)
                        uint2 pk = {permpk(p0, p1), permpk(p2, p3)};
                        *(uint2*)(psw + (lane_m + 16 * nb) * 72 + mb * 16 + quad * 4) = pk;
                    }
                    psum += __shfl_xor(psum, 16);
                    psum += __shfl_xor(psum, 32);
                    l_i[nb] = l_i[nb] * alpha + psum;
#pragma unroll
                    for (int md = 0; md < 4; md++) o_acc[md][nb] *= alpha;
                }
                // no barrier: Ps region is per-wave

                // ---- O^T += V^T * P^T ----
#pragma unroll
                for (int ks = 0; ks < 2; ks++) {
                    shortx8 vF[4], pF[2];
#pragma unroll
                    for (int md = 0; md < 4; md++) {
                        const int r = md * 16 + lane_m;
                        vF[md] = *(const shortx8*)(vb + r * 64 + (((ks * 4 + quad) ^ (r & 7)) * 8));
                    }
#pragma unroll
                    for (int nb = 0; nb < 2; nb++)
                        pF[nb] = *(const shortx8*)(psw + (lane_m + 16 * nb) * 72 + ks * 32 + quad * 8);
#pragma unroll
                    for (int md = 0; md < 4; md++)
#pragma unroll
                        for (int nb = 0; nb < 2; nb++)
                            o_acc[md][nb] = __builtin_amdgcn_mfma_f32_16x16x32_bf16(
                                vF[md], pF[nb], o_acc[md][nb], 0, 0, 0);
                }
            }
        }

        // ---- epilogue: O^T col=q=lane_m+16nb, row=d=16md+quad*4+r ----
#pragma unroll
        for (int nb = 0; nb < 2; nb++) {
            const float inv = 1.0f / l_i[nb];
            const int qg = qw0 + nb * 16 + lane_m;
            const size_t base = ((size_t)b * 2048 + qg) * 1024 + h * 64;
#pragma unroll
            for (int md = 0; md < 4; md++) {
                *(unsigned long long*)(Og + base + md * 16 + quad * 4) =
                    pack4(o_acc[md][nb][0] * inv, o_acc[md][nb][1] * inv,
                          o_acc[md][nb][2] * inv, o_acc[md][nb][3] * inv);
            }
        }
    }
}

// ---------------------------------------------------------------------------
extern "C" void kernel_launch(void* const* d_in, const int* in_sizes, int n_in,
                              void* d_out, int out_size, void* d_ws, size_t ws_size,
                              hipStream_t stream) {
    const void* x      = d_in[0];
    const void* w_attn = d_in[2];
    const void* b_attn = d_in[3];
    const void* w_proj = d_in[4];
    const void* b_proj = d_in[5];

    u16* qws = (u16*)d_ws;                 // 8388608
    u16* kws = qws + 8388608;
    u16* vws = kws + 8388608;              // holds V^T [bh][d][s]
    u16* xb  = vws + 8388608;              // x normalized to bf16
    u16* aws = xb;                         // attn output aliases xb
    u16* wtA = xb + 8388608;               // w_attn^T: 3072x1024
    u16* wtP = wtA + 3145728;              // w_proj^T: 1024x1024
    u16* bAb = wtP + 1048576;              // 3072
    u16* bPb = bAb + 3072;                 // 1024
    int* flag = (int*)(bPb + 1024);

    detect_dtype<<<1, 64, 0, stream>>>((const unsigned int*)x, flag);
    convert_x<<<4096, 256, 0, stream>>>(x, xb, flag);
    convert_bias<<<1, 256, 0, stream>>>(b_attn, b_proj, bAb, bPb, flag);
    transpose_any<<<dim3(3072 / 32, 1024 / 32), 256, 0, stream>>>(w_attn, wtA, 1024, 3072, flag);
    transpose_any<<<dim3(1024 / 32, 1024 / 32), 256, 0, stream>>>(w_proj, wtP, 1024, 1024, flag);

    gemm_bt<1><<<dim3(8192 / 128, 3072 / 128), 256, 0, stream>>>(
        xb, wtA, bAb, nullptr, 8192, 3072, 1024, qws, kws, vws, flag);

    attn_kernel<<<dim3(8, B_ * H_), 256, 0, stream>>>(qws, kws, vws, aws);

    gemm_bt<0><<<dim3(8192 / 128, 1024 / 128), 256, 0, stream>>>(
        aws, wtP, bPb, d_out, 8192, 1024, 1024, nullptr, nullptr, nullptr, flag);
}